// Round 1
// baseline (355.300 us; speedup 1.0000x reference)
//
#include <hip/hip_runtime.h>

// ---------------------------------------------------------------------------
// CanonicalLinear: out[b,c] = sum_n factor[n] * (x @ W[n]^T + b[n])[b,c]
// Collapse heads first: Weff = sum_n factor[n]*W[n]  (C x D),
//                       beff = sum_n factor[n]*b[n]  (C)
// then out = x @ Weff^T + beff  -- single bf16 MFMA GEMM (m97 structure).
// Shapes: B=8192, D=2048, C=2048, N=8 (fp32 in, fp32 out).
// ---------------------------------------------------------------------------

#define MDIM 8192
#define KDIM 2048
#define NDIM 2048
#define NHEADS 8

#define BM 128
#define BN 128
#define BK 64

using bf16x8 = __attribute__((ext_vector_type(8))) short;   // 8 bf16 in 4 VGPRs
using f32x4  = __attribute__((ext_vector_type(4))) float;   // MFMA accumulator

// round-to-nearest-even fp32 -> bf16 (bit pattern)
__device__ __forceinline__ unsigned short f2bf(float x) {
    unsigned int u = __float_as_uint(x);
    u += 0x7FFFu + ((u >> 16) & 1u);
    return (unsigned short)(u >> 16);
}

// async global->LDS, 16 B per lane; LDS dest = wave-uniform base + lane*16
__device__ __forceinline__ void async_load16(const void* g, void* l) {
    __builtin_amdgcn_global_load_lds(
        (const __attribute__((address_space(1))) unsigned int*)g,
        (__attribute__((address_space(3))) unsigned int*)l,
        16, 0, 0);
}

// --- prep 1: Weff_bf16[c,d] = bf16( sum_n factor[n] * W[n,c,d] ) ------------
__global__ void reduce_W_kernel(const float* __restrict__ W,
                                const float* __restrict__ factor,
                                unsigned short* __restrict__ Wbf) {
    const size_t CD = (size_t)NDIM * KDIM;
    size_t idx = ((size_t)blockIdx.x * blockDim.x + threadIdx.x) * 4;
    float f[NHEADS];
#pragma unroll
    for (int n = 0; n < NHEADS; ++n) f[n] = factor[n];
    float ax = 0.f, ay = 0.f, az = 0.f, aw = 0.f;
#pragma unroll
    for (int n = 0; n < NHEADS; ++n) {
        float4 v = *reinterpret_cast<const float4*>(W + (size_t)n * CD + idx);
        ax += f[n] * v.x; ay += f[n] * v.y; az += f[n] * v.z; aw += f[n] * v.w;
    }
    ushort4 o;
    o.x = f2bf(ax); o.y = f2bf(ay); o.z = f2bf(az); o.w = f2bf(aw);
    *reinterpret_cast<ushort4*>(Wbf + idx) = o;
}

// --- prep 2: x -> bf16 ------------------------------------------------------
__global__ void cast_x_kernel(const float* __restrict__ x,
                              unsigned short* __restrict__ xbf) {
    size_t idx = ((size_t)blockIdx.x * blockDim.x + threadIdx.x) * 4;
    float4 v = *reinterpret_cast<const float4*>(x + idx);
    ushort4 o;
    o.x = f2bf(v.x); o.y = f2bf(v.y); o.z = f2bf(v.z); o.w = f2bf(v.w);
    *reinterpret_cast<ushort4*>(xbf + idx) = o;
}

// --- prep 3: beff[c] = sum_n factor[n] * b[n,c] -----------------------------
__global__ void bias_kernel(const float* __restrict__ b,
                            const float* __restrict__ factor,
                            float* __restrict__ beff) {
    int c = blockIdx.x * blockDim.x + threadIdx.x;
    if (c < NDIM) {
        float s = 0.f;
#pragma unroll
        for (int n = 0; n < NHEADS; ++n) s += factor[n] * b[(size_t)n * NDIM + c];
        beff[c] = s;
    }
}

// --- GEMM: out[m,c] = sum_k A[m,k]*B[c,k] + bias[c]  (B^T layout) -----------
__global__ __launch_bounds__(256) void gemm_bt_kernel(
    const unsigned short* __restrict__ A,   // xbf  [MDIM][KDIM]
    const unsigned short* __restrict__ B,   // Wbf  [NDIM][KDIM]
    const float* __restrict__ bias,         // beff [NDIM]
    float* __restrict__ C)                  // out  [MDIM][NDIM] fp32
{
    __shared__ unsigned short As[BM * BK];  // 16 KB, unpadded (global_load_lds)
    __shared__ unsigned short Bs[BN * BK];  // 16 KB

    const int tid  = threadIdx.x;
    const int lane = tid & 63;
    const int w    = tid >> 6;      // wave 0..3
    const int m16  = lane & 15;
    const int quad = lane >> 4;     // 0..3

    const int blockN0 = blockIdx.x * BN;
    const int blockM0 = blockIdx.y * BM;

    const int wr = (w >> 1) * 64;   // wave's row quadrant in tile
    const int wc = (w & 1) * 64;    // wave's col quadrant

    // staging: each thread deposits 16 B; chunk i covers rows [i*32+w*8, +8)
    const int srow = lane >> 3;            // 0..7
    const int scol = (lane & 7) * 8;       // bf16 element col 0..56
    const unsigned short* aP[4];
    const unsigned short* bP[4];
    unsigned short* aL[4];
    unsigned short* bL[4];
#pragma unroll
    for (int i = 0; i < 4; ++i) {
        int r = i * 32 + w * 8;
        aP[i] = A + (size_t)(blockM0 + r + srow) * KDIM + scol;
        bP[i] = B + (size_t)(blockN0 + r + srow) * KDIM + scol;
        aL[i] = As + (size_t)r * BK;       // wave-uniform LDS base
        bL[i] = Bs + (size_t)r * BK;
    }

    f32x4 acc[4][4] = {};

    for (int k0 = 0; k0 < KDIM; k0 += BK) {
#pragma unroll
        for (int i = 0; i < 4; ++i) {
            async_load16(aP[i], aL[i]);
            async_load16(bP[i], bL[i]);
            aP[i] += BK; bP[i] += BK;
        }
        __syncthreads();   // drains vmcnt -> LDS tiles ready

#pragma unroll
        for (int kk = 0; kk < BK; kk += 32) {
            bf16x8 af[4], bfr[4];
#pragma unroll
            for (int rt = 0; rt < 4; ++rt)
                af[rt] = *reinterpret_cast<const bf16x8*>(
                    &As[(size_t)(wr + rt * 16 + m16) * BK + kk + quad * 8]);
#pragma unroll
            for (int ct = 0; ct < 4; ++ct)
                bfr[ct] = *reinterpret_cast<const bf16x8*>(
                    &Bs[(size_t)(wc + ct * 16 + m16) * BK + kk + quad * 8]);
#pragma unroll
            for (int rt = 0; rt < 4; ++rt)
#pragma unroll
                for (int ct = 0; ct < 4; ++ct)
                    acc[rt][ct] = __builtin_amdgcn_mfma_f32_16x16x32_bf16(
                        af[rt], bfr[ct], acc[rt][ct], 0, 0, 0);
        }
        __syncthreads();   // all waves done reading before next overwrite
    }

    // epilogue: C/D layout col=lane&15, row=quad*4+reg (verified m89/m91)
    float bv[4];
#pragma unroll
    for (int ct = 0; ct < 4; ++ct) bv[ct] = bias[blockN0 + wc + ct * 16 + m16];
#pragma unroll
    for (int rt = 0; rt < 4; ++rt) {
        int row0 = blockM0 + wr + rt * 16 + quad * 4;
#pragma unroll
        for (int ct = 0; ct < 4; ++ct) {
            int col = blockN0 + wc + ct * 16 + m16;
#pragma unroll
            for (int r = 0; r < 4; ++r)
                C[(size_t)(row0 + r) * NDIM + col] = acc[rt][ct][r] + bv[ct];
        }
    }
}

extern "C" void kernel_launch(void* const* d_in, const int* in_sizes, int n_in,
                              void* d_out, int out_size, void* d_ws, size_t ws_size,
                              hipStream_t stream) {
    const float* x      = (const float*)d_in[0];   // [8192][2048]
    const float* W      = (const float*)d_in[1];   // [8][2048][2048]
    const float* b      = (const float*)d_in[2];   // [8][2048]
    const float* factor = (const float*)d_in[3];   // [8]
    float* out = (float*)d_out;                    // [8192][2048]

    // workspace layout
    unsigned short* xbf = (unsigned short*)d_ws;                          // 33,554,432 B
    unsigned short* Wbf = (unsigned short*)((char*)d_ws + 33554432);      //  8,388,608 B
    float*          beff = (float*)((char*)d_ws + 33554432 + 8388608);    //      8,192 B

    // prep
    reduce_W_kernel<<<dim3((NDIM * KDIM / 4) / 256), dim3(256), 0, stream>>>(W, factor, Wbf);
    cast_x_kernel<<<dim3(((size_t)MDIM * KDIM / 4) / 256), dim3(256), 0, stream>>>(x, xbf);
    bias_kernel<<<dim3(NDIM / 256), dim3(256), 0, stream>>>(b, factor, beff);

    // GEMM: grid = (N tiles, M tiles)
    gemm_bt_kernel<<<dim3(NDIM / BN, MDIM / BM), dim3(256), 0, stream>>>(xbf, Wbf, beff, out);
}

// Round 2
// 328.791 us; speedup vs baseline: 1.0806x; 1.0806x over previous
//
#include <hip/hip_runtime.h>

// ---------------------------------------------------------------------------
// CanonicalLinear: out[b,c] = sum_n factor[n] * (x @ W[n]^T + b[n])[b,c]
// Collapse heads: Weff = sum_n factor[n]*W[n] (C x D), beff = sum_n factor[n]*b[n]
// then out = x @ Weff^T + beff  -- single bf16 MFMA GEMM (m97 structure).
// Round 2: fused prep kernel; XOR-swizzled LDS (kill 16-way bank conflicts);
//          XCD-aware block swizzle (B-slab L2-resident per XCD).
// ---------------------------------------------------------------------------

#define MDIM 8192
#define KDIM 2048
#define NDIM 2048
#define NHEADS 8

#define BM 128
#define BN 128
#define BK 64

using bf16x8 = __attribute__((ext_vector_type(8))) short;
using f32x4  = __attribute__((ext_vector_type(4))) float;

__device__ __forceinline__ unsigned short f2bf(float x) {
    unsigned int u = __float_as_uint(x);
    u += 0x7FFFu + ((u >> 16) & 1u);
    return (unsigned short)(u >> 16);
}

__device__ __forceinline__ void async_load16(const void* g, void* l) {
    __builtin_amdgcn_global_load_lds(
        (const __attribute__((address_space(1))) unsigned int*)g,
        (__attribute__((address_space(3))) unsigned int*)l,
        16, 0, 0);
}

// --- fused prep: W-reduce -> bf16, x -> bf16, bias reduce -------------------
// blocks [0, 4096):        Wbf[c,d] = bf16(sum_n f[n]*W[n,c,d])   (4 elem/thread)
// blocks [4096, 20480):    xbf = bf16(x)                          (4 elem/thread)
// blocks [20480, 20488):   beff[c] = sum_n f[n]*b[n,c]
__global__ void prep_kernel(const float* __restrict__ x,
                            const float* __restrict__ W,
                            const float* __restrict__ b,
                            const float* __restrict__ factor,
                            unsigned short* __restrict__ xbf,
                            unsigned short* __restrict__ Wbf,
                            float* __restrict__ beff) {
    const int blk = blockIdx.x;
    if (blk < 4096) {
        const size_t CD = (size_t)NDIM * KDIM;
        size_t idx = ((size_t)blk * blockDim.x + threadIdx.x) * 4;
        float f[NHEADS];
#pragma unroll
        for (int n = 0; n < NHEADS; ++n) f[n] = factor[n];
        float ax = 0.f, ay = 0.f, az = 0.f, aw = 0.f;
#pragma unroll
        for (int n = 0; n < NHEADS; ++n) {
            float4 v = *reinterpret_cast<const float4*>(W + (size_t)n * CD + idx);
            ax += f[n] * v.x; ay += f[n] * v.y; az += f[n] * v.z; aw += f[n] * v.w;
        }
        ushort4 o;
        o.x = f2bf(ax); o.y = f2bf(ay); o.z = f2bf(az); o.w = f2bf(aw);
        *reinterpret_cast<ushort4*>(Wbf + idx) = o;
    } else if (blk < 20480) {
        size_t idx = ((size_t)(blk - 4096) * blockDim.x + threadIdx.x) * 4;
        float4 v = *reinterpret_cast<const float4*>(x + idx);
        ushort4 o;
        o.x = f2bf(v.x); o.y = f2bf(v.y); o.z = f2bf(v.z); o.w = f2bf(v.w);
        *reinterpret_cast<ushort4*>(xbf + idx) = o;
    } else {
        int c = (blk - 20480) * blockDim.x + threadIdx.x;
        float s = 0.f;
#pragma unroll
        for (int n = 0; n < NHEADS; ++n) s += factor[n] * b[(size_t)n * NDIM + c];
        beff[c] = s;
    }
}

// --- GEMM: out[m,c] = sum_k A[m,k]*B[c,k] + bias[c]  (B^T layout) -----------
__global__ __launch_bounds__(256) void gemm_bt_kernel(
    const unsigned short* __restrict__ A,   // xbf  [MDIM][KDIM]
    const unsigned short* __restrict__ B,   // Wbf  [NDIM][KDIM]
    const float* __restrict__ bias,         // beff [NDIM]
    float* __restrict__ C)                  // out  [MDIM][NDIM] fp32
{
    __shared__ unsigned short As[BM * BK];  // 16 KB, unpadded (global_load_lds)
    __shared__ unsigned short Bs[BN * BK];  // 16 KB

    const int tid  = threadIdx.x;
    const int lane = tid & 63;
    const int w    = tid >> 6;      // wave 0..3
    const int m16  = lane & 15;
    const int quad = lane >> 4;     // 0..3

    // XCD-aware swizzle: xcd = bid&7 owns N-tiles {2*xcd, 2*xcd+1} (1 MB of B
    // -> L2-resident per XCD); A streams through once per XCD.
    const int bid = blockIdx.x;
    const int g   = bid >> 3;
    const int nt  = (bid & 7) * 2 + (g & 1);
    const int mt  = g >> 1;
    const int blockN0 = nt * BN;
    const int blockM0 = mt * BM;

    const int wr = (w >> 1) * 64;   // wave's row quadrant in tile
    const int wc = (w & 1) * 64;    // wave's col quadrant

    // staging: lane deposits 16 B at LDS slot (srow, lane&7)  [HW-fixed order];
    // we XOR-swizzle the GLOBAL column group so LDS group gl holds global
    // group gl ^ (row&7) -> fragment reads spread across all 8 bank-groups.
    const int srow = lane >> 3;                    // 0..7 (row&7 of this lane's row)
    const int scol = ((lane & 7) ^ srow) * 8;      // swizzled global bf16 col
    const unsigned short* aP[4];
    const unsigned short* bP[4];
    unsigned short* aL[4];
    unsigned short* bL[4];
#pragma unroll
    for (int i = 0; i < 4; ++i) {
        int r = i * 32 + w * 8;
        aP[i] = A + (size_t)(blockM0 + r + srow) * KDIM + scol;
        bP[i] = B + (size_t)(blockN0 + r + srow) * KDIM + scol;
        aL[i] = As + (size_t)r * BK;               // wave-uniform LDS base
        bL[i] = Bs + (size_t)r * BK;
    }

    f32x4 acc[4][4] = {};

    for (int k0 = 0; k0 < KDIM; k0 += BK) {
#pragma unroll
        for (int i = 0; i < 4; ++i) {
            async_load16(aP[i], aL[i]);
            async_load16(bP[i], bL[i]);
            aP[i] += BK; bP[i] += BK;
        }
        __syncthreads();

#pragma unroll
        for (int kk = 0; kk < BK; kk += 32) {
            bf16x8 af[4], bfr[4];
#pragma unroll
            for (int rt = 0; rt < 4; ++rt) {
                int row = wr + rt * 16 + m16;
                int gA = ((kk >> 3) + quad) ^ (row & 7);   // un-swizzle
                af[rt] = *reinterpret_cast<const bf16x8*>(&As[(size_t)row * BK + gA * 8]);
            }
#pragma unroll
            for (int ct = 0; ct < 4; ++ct) {
                int row = wc + ct * 16 + m16;
                int gB = ((kk >> 3) + quad) ^ (row & 7);
                bfr[ct] = *reinterpret_cast<const bf16x8*>(&Bs[(size_t)row * BK + gB * 8]);
            }
#pragma unroll
            for (int rt = 0; rt < 4; ++rt)
#pragma unroll
                for (int ct = 0; ct < 4; ++ct)
                    acc[rt][ct] = __builtin_amdgcn_mfma_f32_16x16x32_bf16(
                        af[rt], bfr[ct], acc[rt][ct], 0, 0, 0);
        }
        __syncthreads();
    }

    // epilogue: C/D layout col=lane&15, row=quad*4+reg (verified m89/m91)
    float bv[4];
#pragma unroll
    for (int ct = 0; ct < 4; ++ct) bv[ct] = bias[blockN0 + wc + ct * 16 + m16];
#pragma unroll
    for (int rt = 0; rt < 4; ++rt) {
        int row0 = blockM0 + wr + rt * 16 + quad * 4;
#pragma unroll
        for (int ct = 0; ct < 4; ++ct) {
            int col = blockN0 + wc + ct * 16 + m16;
#pragma unroll
            for (int r = 0; r < 4; ++r)
                C[(size_t)(row0 + r) * NDIM + col] = acc[rt][ct][r] + bv[ct];
        }
    }
}

extern "C" void kernel_launch(void* const* d_in, const int* in_sizes, int n_in,
                              void* d_out, int out_size, void* d_ws, size_t ws_size,
                              hipStream_t stream) {
    const float* x      = (const float*)d_in[0];   // [8192][2048]
    const float* W      = (const float*)d_in[1];   // [8][2048][2048]
    const float* b      = (const float*)d_in[2];   // [8][2048]
    const float* factor = (const float*)d_in[3];   // [8]
    float* out = (float*)d_out;                    // [8192][2048]

    unsigned short* xbf  = (unsigned short*)d_ws;                         // 33,554,432 B
    unsigned short* Wbf  = (unsigned short*)((char*)d_ws + 33554432);     //  8,388,608 B
    float*          beff = (float*)((char*)d_ws + 33554432 + 8388608);    //      8,192 B

    prep_kernel<<<dim3(20488), dim3(256), 0, stream>>>(x, W, b, factor, xbf, Wbf, beff);
    gemm_bt_kernel<<<dim3(1024), dim3(256), 0, stream>>>(xbf, Wbf, beff, out);
}